// Round 8
// baseline (266.352 us; speedup 1.0000x reference)
//
#include <hip/hip_runtime.h>
#include <hip/hip_bf16.h>
#include <math.h>

#define BB 8
#define NN 2048
#define DD 128
#define LL 3
#define GN_EPS 1e-5f

typedef __attribute__((ext_vector_type(8))) short bf16x8;
typedef __attribute__((ext_vector_type(4))) float f32x4;

// raw v_sqrt_f32 (1 inst)
#define FSQRT(x) __builtin_amdgcn_sqrtf(x)

// round-half-up f32 -> bf16 bits
__device__ __forceinline__ unsigned short f2bf(float f) {
    union { float f; unsigned u; } v; v.f = f;
    return (unsigned short)((v.u + 0x8000u) >> 16);
}

__device__ __forceinline__ float fast_tanh(float x) {
    float e = __expf(-2.0f * fabsf(x));
    float t = (1.0f - e) * __builtin_amdgcn_rcpf(1.0f + e);
    return copysignf(t, x);
}

// GraphNorm affine fold: h_norm = s*h + c
__device__ __forceinline__ void stats_sc(float ps, float pq, float a, float w_,
                                         float b_, float& s, float& c) {
    const float inv_n = 1.0f / (float)NN;
    float mean = ps * inv_n;
    float msq  = pq * inv_n;
    float var  = msq - mean * mean * a * (2.0f - a);
    float rstd = rsqrtf(var + GN_EPS);
    s = w_ * rstd;
    c = b_ - s * (a * mean);
}

// ---------------------------------------------------------------------------
// K0: prep_wg — pack Wg (3x128x128 f32) into bf16 MFMA frag order.
// wgf[...] = Wg[l][dpt*16+ll][kc*32+lq*8+e]
// ---------------------------------------------------------------------------
__global__ __launch_bounds__(256)
void prep_wg(const float* __restrict__ Wg, unsigned short* __restrict__ wgf)
{
    const int f = blockIdx.x * 256 + threadIdx.x;    // < 3*128*128
    const int l  = f >> 14;
    const int r  = f & 16383;
    const int dp = r >> 7;
    const int e  = r & 127;
    const int dpt = dp >> 4, ll = dp & 15;
    const int kc  = e >> 5,  eo = e & 31;
    wgf[((((l * 8 + dpt) * 4 + kc) * 16 + ll) << 5) + eo] = f2bf(Wg[f]);
}

// ---------------------------------------------------------------------------
// K1: deg — dinv[b][n] = rsqrt( sum_m dist(n,m) + 1 ).  Fast sqrt.
// ---------------------------------------------------------------------------
__global__ __launch_bounds__(256)
void deg_kernel(const float* __restrict__ inst, float* __restrict__ dinv)
{
    __shared__ float cs[NN * 2];
    const int b   = blockIdx.x >> 6;
    const int n0  = (blockIdx.x & 63) * 32;
    const int tid = threadIdx.x;
    const int w    = tid >> 6;
    const int lane = tid & 63;

    const float* instb = inst + b * NN * 2;
    for (int i = tid; i < (NN * 2) / 4; i += 256)
        ((float4*)cs)[i] = ((const float4*)instb)[i];
    __syncthreads();

    float mx[4][8], my[4][8];
    #pragma unroll
    for (int c = 0; c < 4; ++c)
        #pragma unroll
        for (int e = 0; e < 8; ++e) {
            int m = c * 512 + lane * 8 + e;
            mx[c][e] = cs[m * 2 + 0];
            my[c][e] = cs[m * 2 + 1];
        }

    for (int r = 0; r < 8; ++r) {
        const int n = n0 + w * 8 + r;
        const float nxv = cs[n * 2 + 0];
        const float nyv = cs[n * 2 + 1];
        float rs = 0.f;
        #pragma unroll
        for (int c = 0; c < 4; ++c)
            #pragma unroll
            for (int e = 0; e < 8; ++e) {
                float dx = nxv - mx[c][e];
                float dy = nyv - my[c][e];
                rs += FSQRT(dx * dx + dy * dy);   // diag contributes 0
            }
        #pragma unroll
        for (int off = 1; off < 64; off <<= 1) rs += __shfl_xor(rs, off);
        if (lane == 0) dinv[b * NN + n] = rsqrtf(rs + 1.0f);
    }
}

// ---------------------------------------------------------------------------
// K2: proj_node + zero all per-layer stats buffers
// ---------------------------------------------------------------------------
__global__ __launch_bounds__(256)
void proj_kernel(const float* __restrict__ inst, const float* __restrict__ Wn,
                 const float* __restrict__ bn, float* __restrict__ h,
                 float* __restrict__ psum, float* __restrict__ psq)
{
    const int idx = blockIdx.x * 256 + threadIdx.x;
    const int d   = idx & (DD - 1);
    const int row = idx >> 7;
    const float x0 = inst[row * 2 + 0];
    const float x1 = inst[row * 2 + 1];
    h[idx] = x0 * Wn[d * 2 + 0] + x1 * Wn[d * 2 + 1] + bn[d];
    if (blockIdx.x == 0) {
        for (int i = threadIdx.x; i < LL * BB * DD; i += 256) {
            psum[i] = 0.0f; psq[i] = 0.0f;
        }
    }
}

// ---------------------------------------------------------------------------
// K3: lin (MFMA). tT[b][d'][m] = bf16( dinv[m] * sum_e norm(h)[m][e]*Wg[d'][e] )
// Operand order: A = h-frag (M=node), B = Wg-frag (N=d') -> C lane holds
// fixed d' (=ll), 4 consecutive nodes (reg) -> coalesced ushort4 stores.
// ---------------------------------------------------------------------------
template <bool HP>
__global__ __launch_bounds__(256)
void lin_mfma(const float* __restrict__ h, const unsigned short* __restrict__ wgf_l,
              const float* __restrict__ dinv,
              const float* __restrict__ psumP, const float* __restrict__ psqP,
              const float* __restrict__ ga, const float* __restrict__ gw,
              const float* __restrict__ gb, unsigned short* __restrict__ tT)
{
    __shared__ float sL[DD], cL[DD];
    const int tid  = threadIdx.x;
    const int row0 = blockIdx.x * 32;
    const int b    = row0 >> 11;
    const int w    = tid >> 6;
    const int lane = tid & 63;
    const int lq   = lane >> 4;
    const int ll   = lane & 15;

    if (tid < DD) {
        float s = 1.0f, c = 0.0f;
        if (HP)
            stats_sc(psumP[b * DD + tid], psqP[b * DD + tid],
                     ga[tid], gw[tid], gb[tid], s, c);
        sL[tid] = s; cL[tid] = c;
    }
    __syncthreads();

    bf16x8 aw[2][4];
    #pragma unroll
    for (int mt = 0; mt < 2; ++mt) {
        const int dpt = 2 * w + mt;
        #pragma unroll
        for (int kc = 0; kc < 4; ++kc)
            aw[mt][kc] = *(const bf16x8*)&wgf_l[(((dpt * 4 + kc) * 16 + ll) << 5) + lq * 8];
    }

    bf16x8 bh[2][4];
    #pragma unroll
    for (int nt = 0; nt < 2; ++nt) {
        const float* hrow = h + (size_t)(row0 + nt * 16 + ll) * DD;
        #pragma unroll
        for (int kc = 0; kc < 4; ++kc) {
            float4 h0 = *(const float4*)&hrow[kc * 32 + lq * 8];
            float4 h1 = *(const float4*)&hrow[kc * 32 + lq * 8 + 4];
            const int e0 = kc * 32 + lq * 8;
            bf16x8 p;
            p[0] = (short)f2bf(fmaf(sL[e0 + 0], h0.x, cL[e0 + 0]));
            p[1] = (short)f2bf(fmaf(sL[e0 + 1], h0.y, cL[e0 + 1]));
            p[2] = (short)f2bf(fmaf(sL[e0 + 2], h0.z, cL[e0 + 2]));
            p[3] = (short)f2bf(fmaf(sL[e0 + 3], h0.w, cL[e0 + 3]));
            p[4] = (short)f2bf(fmaf(sL[e0 + 4], h1.x, cL[e0 + 4]));
            p[5] = (short)f2bf(fmaf(sL[e0 + 5], h1.y, cL[e0 + 5]));
            p[6] = (short)f2bf(fmaf(sL[e0 + 6], h1.z, cL[e0 + 6]));
            p[7] = (short)f2bf(fmaf(sL[e0 + 7], h1.w, cL[e0 + 7]));
            bh[nt][kc] = p;
        }
    }

    f32x4 acc[2][2];   // [nt][mt]
    #pragma unroll
    for (int i = 0; i < 2; ++i)
        #pragma unroll
        for (int j = 0; j < 2; ++j) acc[i][j] = (f32x4)0.0f;

    #pragma unroll
    for (int kc = 0; kc < 4; ++kc)
        #pragma unroll
        for (int nt = 0; nt < 2; ++nt)
            #pragma unroll
            for (int mt = 0; mt < 2; ++mt)
                acc[nt][mt] = __builtin_amdgcn_mfma_f32_16x16x32_bf16(
                    bh[nt][kc], aw[mt][kc], acc[nt][mt], 0, 0, 0);

    // store: lane holds d' = (2w+mt)*16+ll, nodes = nbase+nt*16+lq*4+reg
    const int nbase = row0 & (NN - 1);
    #pragma unroll
    for (int nt = 0; nt < 2; ++nt) {
        const int node0 = nbase + nt * 16 + lq * 4;
        float4 di4 = *(const float4*)&dinv[row0 + nt * 16 + lq * 4];
        #pragma unroll
        for (int mt = 0; mt < 2; ++mt) {
            const int dp = (2 * w + mt) * 16 + ll;
            ushort4 pk;
            pk.x = f2bf(acc[nt][mt][0] * di4.x);
            pk.y = f2bf(acc[nt][mt][1] * di4.y);
            pk.z = f2bf(acc[nt][mt][2] * di4.z);
            pk.w = f2bf(acc[nt][mt][3] * di4.w);
            *(ushort4*)&tT[(size_t)(b * DD + dp) * NN + node0] = pk;
        }
    }
}

// ---------------------------------------------------------------------------
// K4: agg — A regenerated in registers (fast sqrt), self-loop on diagonal.
// C[n][d] = sum_m (dist+I)[n][m] * t[m][d].
// Block 32n x 128d, grid 512 = [ntile(6b)<<3 | b(3b)] (batch -> XCD).
// 4 waves = 4-way K-split (wave w: m in [w*512,(w+1)*512)), 16 chunks of 32.
// Operands swapped: mfma(tT-frag, dist-frag) -> lane holds fixed n (=ll),
// 4 consecutive d -> float4 epilogue.  2-round 32KB LDS reduction.
// ---------------------------------------------------------------------------
template <bool HP>
__global__ __launch_bounds__(256, 2)
void agg_mfma(const float* __restrict__ inst, const unsigned short* __restrict__ tT,
              const float* __restrict__ dinv, const float* __restrict__ bg_l,
              const float* __restrict__ psumP, const float* __restrict__ psqP,
              const float* __restrict__ ga, const float* __restrict__ gw,
              const float* __restrict__ gb,
              float* __restrict__ h, float* __restrict__ psum, float* __restrict__ psq)
{
    __shared__ float cs[NN * 2];          // 16 KB coords
    __shared__ f32x4 red[4][8][64];       // 32 KB reduction buffer
    const int b    = blockIdx.x & 7;
    const int n0   = (blockIdx.x >> 3) * 32;
    const int tid  = threadIdx.x;
    const int w    = tid >> 6;
    const int lane = tid & 63;
    const int lq   = lane >> 4;
    const int ll   = lane & 15;

    const float* instb = inst + b * NN * 2;
    for (int i = tid; i < (NN * 2) / 4; i += 256)
        ((float4*)cs)[i] = ((const float4*)instb)[i];
    __syncthreads();

    // n-coords for this lane's 2 B-frag rows (n = n0 + nt*16 + ll)
    float nx[2], ny[2];
    #pragma unroll
    for (int nt = 0; nt < 2; ++nt) {
        int n = n0 + nt * 16 + ll;
        nx[nt] = cs[n * 2 + 0];
        ny[nt] = cs[n * 2 + 1];
    }

    // tT pointers (A-operand): row d = dt*16+ll, this wave's K-range
    const unsigned short* tTb = tT + (size_t)b * DD * NN + w * 512 + lq * 8;
    const unsigned short* gbp[8];
    #pragma unroll
    for (int dt = 0; dt < 8; ++dt)
        gbp[dt] = tTb + (size_t)(dt * 16 + ll) * NN;

    f32x4 acc[2][8];   // [nt][dt]
    #pragma unroll
    for (int i = 0; i < 2; ++i)
        #pragma unroll
        for (int j = 0; j < 8; ++j) acc[i][j] = (f32x4)0.0f;

    const int mwbase = w * 512;

    #pragma unroll 2
    for (int kc = 0; kc < 16; ++kc) {
        const int mo = kc * 32;
        const int mb = mwbase + mo;          // chunk base (wave-uniform)

        // A-frags (tT) for this chunk — issued first to overlap with dist VALU
        bf16x8 fb[8];
        #pragma unroll
        for (int dt = 0; dt < 8; ++dt)
            fb[dt] = *(const bf16x8*)(gbp[dt] + mo);

        // m-coords from LDS: this lane's 8 m's (m = mb + lq*8 + j)
        const float* cp = &cs[(mb + lq * 8) * 2];
        float4 c01 = *(const float4*)(cp + 0);
        float4 c23 = *(const float4*)(cp + 4);
        float4 c45 = *(const float4*)(cp + 8);
        float4 c67 = *(const float4*)(cp + 12);
        float mx[8] = { c01.x, c01.z, c23.x, c23.z, c45.x, c45.z, c67.x, c67.z };
        float my[8] = { c01.y, c01.w, c23.y, c23.w, c45.y, c45.w, c67.y, c67.w };

        // B-frags: dist(n = n0+nt*16+ll, m = mb+lq*8+j); diag = 1.0
        const bool diagchunk = (mb == n0);
        bf16x8 bf[2];
        #pragma unroll
        for (int nt = 0; nt < 2; ++nt) {
            float dist[8];
            #pragma unroll
            for (int j = 0; j < 8; ++j) {
                float dx = nx[nt] - mx[j];
                float dy = ny[nt] - my[j];
                dist[j] = FSQRT(dx * dx + dy * dy);
            }
            if (diagchunk) {
                const int nloc = nt * 16 + ll;
                const int base = lq * 8;
                #pragma unroll
                for (int j = 0; j < 8; ++j)
                    if (base + j == nloc) dist[j] = 1.0f;   // self-loop
            }
            union { bf16x8 v; __hip_bfloat162 h2[4]; } u;
            #pragma unroll
            for (int p = 0; p < 4; ++p)
                u.h2[p] = __float22bfloat162_rn(make_float2(dist[2 * p], dist[2 * p + 1]));
            bf[nt] = u.v;
        }

        #pragma unroll
        for (int dt = 0; dt < 8; ++dt)
            #pragma unroll
            for (int nt = 0; nt < 2; ++nt)
                acc[nt][dt] = __builtin_amdgcn_mfma_f32_16x16x32_bf16(
                    fb[dt], bf[nt], acc[nt][dt], 0, 0, 0);
    }

    // ---- cross-wave reduction + fused epilogue (2 rounds of 8 frags)
    __syncthreads();
    #pragma unroll
    for (int round = 0; round < 2; ++round) {
        #pragma unroll
        for (int nt = 0; nt < 2; ++nt)
            #pragma unroll
            for (int fd = 0; fd < 4; ++fd)
                red[w][nt * 4 + fd][lane] = acc[nt][round * 4 + fd];
        __syncthreads();

        #pragma unroll
        for (int i = 0; i < 2; ++i) {
            const int f  = w * 2 + i;
            const int nt = f >> 2;
            const int dt = round * 4 + (f & 3);
            f32x4 v = red[0][f][lane];
            v += red[1][f][lane];
            v += red[2][f][lane];
            v += red[3][f][lane];

            const int n  = n0 + nt * 16 + ll;
            const int d0 = dt * 16 + lq * 4;
            const float di = dinv[b * NN + n];
            float4 bg4 = *(const float4*)&bg_l[d0];
            float sres[4] = {1.f, 1.f, 1.f, 1.f}, cres[4] = {0.f, 0.f, 0.f, 0.f};
            if (HP) {
                float4 ps4 = *(const float4*)&psumP[b * DD + d0];
                float4 pq4 = *(const float4*)&psqP[b * DD + d0];
                float4 ga4 = *(const float4*)&ga[d0];
                float4 gw4 = *(const float4*)&gw[d0];
                float4 gb4 = *(const float4*)&gb[d0];
                stats_sc(ps4.x, pq4.x, ga4.x, gw4.x, gb4.x, sres[0], cres[0]);
                stats_sc(ps4.y, pq4.y, ga4.y, gw4.y, gb4.y, sres[1], cres[1]);
                stats_sc(ps4.z, pq4.z, ga4.z, gw4.z, gb4.z, sres[2], cres[2]);
                stats_sc(ps4.w, pq4.w, ga4.w, gw4.w, gb4.w, sres[3], cres[3]);
            }
            size_t idx = ((size_t)b * NN + n) * DD + d0;
            float4 hv = *(const float4*)&h[idx];
            float outv[4];
            #pragma unroll
            for (int r = 0; r < 4; ++r) {
                float pre = di * v[r] + (&bg4.x)[r];
                outv[r] = fast_tanh(pre) + fmaf(sres[r], (&hv.x)[r], cres[r]);
            }
            float4 ov = { outv[0], outv[1], outv[2], outv[3] };
            *(float4*)&h[idx] = ov;

            // stats: per-d sums over the 16 n's (ll dimension)
            float hs[4], hq[4];
            #pragma unroll
            for (int r = 0; r < 4; ++r) { hs[r] = outv[r]; hq[r] = outv[r] * outv[r]; }
            #pragma unroll
            for (int off = 1; off < 16; off <<= 1) {
                #pragma unroll
                for (int r = 0; r < 4; ++r) {
                    hs[r] += __shfl_xor(hs[r], off);
                    hq[r] += __shfl_xor(hq[r], off);
                }
            }
            if (ll == 0) {
                #pragma unroll
                for (int r = 0; r < 4; ++r) {
                    atomicAdd(&psum[b * DD + d0 + r], hs[r]);
                    atomicAdd(&psq[b * DD + d0 + r], hq[r]);
                }
            }
        }
        __syncthreads();
    }
}

// ---------------------------------------------------------------------------
// K5: final apply with in-thread stats from layer-2 buffers
// ---------------------------------------------------------------------------
__global__ __launch_bounds__(256)
void apply_kernel(const float* __restrict__ h,
                  const float* __restrict__ psum2, const float* __restrict__ psq2,
                  const float* __restrict__ ga, const float* __restrict__ gw,
                  const float* __restrict__ gb, float* __restrict__ dst)
{
    const int i4 = blockIdx.x * 256 + threadIdx.x;    // < B*N*D/4
    const int dg = (i4 & 31) * 4;
    const int b  = i4 >> 16;                          // N*D/4 = 65536
    float4 hv = ((const float4*)h)[i4];
    float o[4];
    #pragma unroll
    for (int j = 0; j < 4; ++j) {
        const int d = dg + j;
        float s, c;
        stats_sc(psum2[b * DD + d], psq2[b * DD + d], ga[d], gw[d], gb[d], s, c);
        o[j] = fmaf(s, (&hv.x)[j], c);
    }
    float4 ov = { o[0], o[1], o[2], o[3] };
    ((float4*)dst)[i4] = ov;
}

// ---------------------------------------------------------------------------
extern "C" void kernel_launch(void* const* d_in, const int* in_sizes, int n_in,
                              void* d_out, int out_size, void* d_ws, size_t ws_size,
                              hipStream_t stream)
{
    const float* inst = (const float*)d_in[0];
    const float* Wn   = (const float*)d_in[1];
    const float* bn   = (const float*)d_in[2];
    const float* Wg   = (const float*)d_in[3];
    const float* bg   = (const float*)d_in[4];
    const float* gw   = (const float*)d_in[5];
    const float* gb   = (const float*)d_in[6];
    const float* ga   = (const float*)d_in[7];
    float* out = (float*)d_out;

    float* ws   = (float*)d_ws;
    float* dinv = ws;                                   // B*N
    float* h    = dinv + BB * NN;                       // B*N*D
    float* psum = h + (size_t)BB * NN * DD;             // LL*B*D
    float* psq  = psum + LL * BB * DD;                  // LL*B*D
    unsigned short* wgf = (unsigned short*)(psq + LL * BB * DD);  // LL*D*D bf16
    unsigned short* tT  = wgf + LL * DD * DD;                     // B*D*N bf16 (8MB)

    prep_wg<<<(LL * DD * DD) / 256, 256, 0, stream>>>(Wg, wgf);
    deg_kernel<<<BB * 64, 256, 0, stream>>>(inst, dinv);
    proj_kernel<<<(BB * NN * DD) / 256, 256, 0, stream>>>(inst, Wn, bn, h, psum, psq);

    for (int l = 0; l < LL; ++l) {
        const unsigned short* wgl = wgf + (size_t)l * DD * DD;
        const float* psP = psum + (size_t)(l - 1) * BB * DD;
        const float* pqP = psq  + (size_t)(l - 1) * BB * DD;
        float* psL = psum + (size_t)l * BB * DD;
        float* pqL = psq  + (size_t)l * BB * DD;
        if (l == 0) {
            lin_mfma<false><<<(BB * NN) / 32, 256, 0, stream>>>(
                h, wgl, dinv, nullptr, nullptr, ga, gw, gb, tT);
            agg_mfma<false><<<(NN / 32) * BB, 256, 0, stream>>>(
                inst, tT, dinv, bg + l * DD, nullptr, nullptr, ga, gw, gb, h, psL, pqL);
        } else {
            lin_mfma<true><<<(BB * NN) / 32, 256, 0, stream>>>(
                h, wgl, dinv, psP, pqP, ga, gw, gb, tT);
            agg_mfma<true><<<(NN / 32) * BB, 256, 0, stream>>>(
                inst, tT, dinv, bg + l * DD, psP, pqP, ga, gw, gb, h, psL, pqL);
        }
    }
    apply_kernel<<<(BB * NN * DD / 4) / 256, 256, 0, stream>>>(
        h, psum + 2 * BB * DD, psq + 2 * BB * DD, ga, gw, gb, out);
}

// Round 9
// 257.749 us; speedup vs baseline: 1.0334x; 1.0334x over previous
//
#include <hip/hip_runtime.h>
#include <hip/hip_bf16.h>
#include <math.h>

#define BB 8
#define NN 2048
#define DD 128
#define LL 3
#define GN_EPS 1e-5f

typedef __attribute__((ext_vector_type(8))) short bf16x8;
typedef __attribute__((ext_vector_type(4))) float f32x4;

// raw v_sqrt_f32 (1 inst)
#define FSQRT(x) __builtin_amdgcn_sqrtf(x)

#define GLL16(gp, lp) __builtin_amdgcn_global_load_lds( \
    (const __attribute__((address_space(1))) void*)(gp), \
    (__attribute__((address_space(3))) void*)(lp), 16, 0, 0)

// s_waitcnt imm: vm_lo[3:0], exp[6:4], lgkm[11:8], vm_hi[15:14]
#define WAIT_VM8   0x0F78   // vmcnt(8),  lgkm nowait, exp nowait
#define WAIT_VM0   0x0F70   // vmcnt(0)
#define WAIT_LGKM0 0xC07F   // lgkmcnt(0), vm nowait

// round-half-up f32 -> bf16 bits
__device__ __forceinline__ unsigned short f2bf(float f) {
    union { float f; unsigned u; } v; v.f = f;
    return (unsigned short)((v.u + 0x8000u) >> 16);
}

__device__ __forceinline__ float fast_tanh(float x) {
    float e = __expf(-2.0f * fabsf(x));
    float t = (1.0f - e) * __builtin_amdgcn_rcpf(1.0f + e);
    return copysignf(t, x);
}

// GraphNorm affine fold: h_norm = s*h + c
__device__ __forceinline__ void stats_sc(float ps, float pq, float a, float w_,
                                         float b_, float& s, float& c) {
    const float inv_n = 1.0f / (float)NN;
    float mean = ps * inv_n;
    float msq  = pq * inv_n;
    float var  = msq - mean * mean * a * (2.0f - a);
    float rstd = rsqrtf(var + GN_EPS);
    s = w_ * rstd;
    c = b_ - s * (a * mean);
}

// ---------------------------------------------------------------------------
// K0: prep_wg — pack Wg (3x128x128 f32) into bf16 MFMA frag order.
// ---------------------------------------------------------------------------
__global__ __launch_bounds__(256)
void prep_wg(const float* __restrict__ Wg, unsigned short* __restrict__ wgf)
{
    const int f = blockIdx.x * 256 + threadIdx.x;    // < 3*128*128
    const int l  = f >> 14;
    const int r  = f & 16383;
    const int dp = r >> 7;
    const int e  = r & 127;
    const int dpt = dp >> 4, ll = dp & 15;
    const int kc  = e >> 5,  eo = e & 31;
    wgf[((((l * 8 + dpt) * 4 + kc) * 16 + ll) << 5) + eo] = f2bf(Wg[f]);
}

// ---------------------------------------------------------------------------
// K1: deg — dinv[b][n] = rsqrt( sum_m dist(n,m) + 1 ).
// ---------------------------------------------------------------------------
__global__ __launch_bounds__(256)
void deg_kernel(const float* __restrict__ inst, float* __restrict__ dinv)
{
    __shared__ float cs[NN * 2];
    const int b   = blockIdx.x >> 6;
    const int n0  = (blockIdx.x & 63) * 32;
    const int tid = threadIdx.x;
    const int w    = tid >> 6;
    const int lane = tid & 63;

    const float* instb = inst + b * NN * 2;
    for (int i = tid; i < (NN * 2) / 4; i += 256)
        ((float4*)cs)[i] = ((const float4*)instb)[i];
    __syncthreads();

    float mx[4][8], my[4][8];
    #pragma unroll
    for (int c = 0; c < 4; ++c)
        #pragma unroll
        for (int e = 0; e < 8; ++e) {
            int m = c * 512 + lane * 8 + e;
            mx[c][e] = cs[m * 2 + 0];
            my[c][e] = cs[m * 2 + 1];
        }

    for (int r = 0; r < 8; ++r) {
        const int n = n0 + w * 8 + r;
        const float nxv = cs[n * 2 + 0];
        const float nyv = cs[n * 2 + 1];
        float rs = 0.f;
        #pragma unroll
        for (int c = 0; c < 4; ++c)
            #pragma unroll
            for (int e = 0; e < 8; ++e) {
                float dx = nxv - mx[c][e];
                float dy = nyv - my[c][e];
                rs += FSQRT(dx * dx + dy * dy);   // diag contributes 0
            }
        #pragma unroll
        for (int off = 1; off < 64; off <<= 1) rs += __shfl_xor(rs, off);
        if (lane == 0) dinv[b * NN + n] = rsqrtf(rs + 1.0f);
    }
}

// ---------------------------------------------------------------------------
// K2: proj_node + zero all per-layer stats buffers
// ---------------------------------------------------------------------------
__global__ __launch_bounds__(256)
void proj_kernel(const float* __restrict__ inst, const float* __restrict__ Wn,
                 const float* __restrict__ bn, float* __restrict__ h,
                 float* __restrict__ psum, float* __restrict__ psq)
{
    const int idx = blockIdx.x * 256 + threadIdx.x;
    const int d   = idx & (DD - 1);
    const int row = idx >> 7;
    const float x0 = inst[row * 2 + 0];
    const float x1 = inst[row * 2 + 1];
    h[idx] = x0 * Wn[d * 2 + 0] + x1 * Wn[d * 2 + 1] + bn[d];
    if (blockIdx.x == 0) {
        for (int i = threadIdx.x; i < LL * BB * DD; i += 256) {
            psum[i] = 0.0f; psq[i] = 0.0f;
        }
    }
}

// ---------------------------------------------------------------------------
// K3: lin (MFMA). tT[b][d'][m] = bf16( dinv[m] * sum_e norm(h)[m][e]*Wg[d'][e] )
// ---------------------------------------------------------------------------
template <bool HP>
__global__ __launch_bounds__(256)
void lin_mfma(const float* __restrict__ h, const unsigned short* __restrict__ wgf_l,
              const float* __restrict__ dinv,
              const float* __restrict__ psumP, const float* __restrict__ psqP,
              const float* __restrict__ ga, const float* __restrict__ gw,
              const float* __restrict__ gb, unsigned short* __restrict__ tT)
{
    __shared__ float sL[DD], cL[DD];
    const int tid  = threadIdx.x;
    const int row0 = blockIdx.x * 32;
    const int b    = row0 >> 11;
    const int w    = tid >> 6;
    const int lane = tid & 63;
    const int lq   = lane >> 4;
    const int ll   = lane & 15;

    if (tid < DD) {
        float s = 1.0f, c = 0.0f;
        if (HP)
            stats_sc(psumP[b * DD + tid], psqP[b * DD + tid],
                     ga[tid], gw[tid], gb[tid], s, c);
        sL[tid] = s; cL[tid] = c;
    }
    __syncthreads();

    bf16x8 aw[2][4];
    #pragma unroll
    for (int mt = 0; mt < 2; ++mt) {
        const int dpt = 2 * w + mt;
        #pragma unroll
        for (int kc = 0; kc < 4; ++kc)
            aw[mt][kc] = *(const bf16x8*)&wgf_l[(((dpt * 4 + kc) * 16 + ll) << 5) + lq * 8];
    }

    bf16x8 bh[2][4];
    #pragma unroll
    for (int nt = 0; nt < 2; ++nt) {
        const float* hrow = h + (size_t)(row0 + nt * 16 + ll) * DD;
        #pragma unroll
        for (int kc = 0; kc < 4; ++kc) {
            float4 h0 = *(const float4*)&hrow[kc * 32 + lq * 8];
            float4 h1 = *(const float4*)&hrow[kc * 32 + lq * 8 + 4];
            const int e0 = kc * 32 + lq * 8;
            bf16x8 p;
            p[0] = (short)f2bf(fmaf(sL[e0 + 0], h0.x, cL[e0 + 0]));
            p[1] = (short)f2bf(fmaf(sL[e0 + 1], h0.y, cL[e0 + 1]));
            p[2] = (short)f2bf(fmaf(sL[e0 + 2], h0.z, cL[e0 + 2]));
            p[3] = (short)f2bf(fmaf(sL[e0 + 3], h0.w, cL[e0 + 3]));
            p[4] = (short)f2bf(fmaf(sL[e0 + 4], h1.x, cL[e0 + 4]));
            p[5] = (short)f2bf(fmaf(sL[e0 + 5], h1.y, cL[e0 + 5]));
            p[6] = (short)f2bf(fmaf(sL[e0 + 6], h1.z, cL[e0 + 6]));
            p[7] = (short)f2bf(fmaf(sL[e0 + 7], h1.w, cL[e0 + 7]));
            bh[nt][kc] = p;
        }
    }

    f32x4 acc[2][2];   // [nt][mt]
    #pragma unroll
    for (int i = 0; i < 2; ++i)
        #pragma unroll
        for (int j = 0; j < 2; ++j) acc[i][j] = (f32x4)0.0f;

    #pragma unroll
    for (int kc = 0; kc < 4; ++kc)
        #pragma unroll
        for (int nt = 0; nt < 2; ++nt)
            #pragma unroll
            for (int mt = 0; mt < 2; ++mt)
                acc[nt][mt] = __builtin_amdgcn_mfma_f32_16x16x32_bf16(
                    bh[nt][kc], aw[mt][kc], acc[nt][mt], 0, 0, 0);

    // store: lane holds d' = (2w+mt)*16+ll, nodes = nbase+nt*16+lq*4+reg
    const int nbase = row0 & (NN - 1);
    #pragma unroll
    for (int nt = 0; nt < 2; ++nt) {
        const int node0 = nbase + nt * 16 + lq * 4;
        float4 di4 = *(const float4*)&dinv[row0 + nt * 16 + lq * 4];
        #pragma unroll
        for (int mt = 0; mt < 2; ++mt) {
            const int dp = (2 * w + mt) * 16 + ll;
            ushort4 pk;
            pk.x = f2bf(acc[nt][mt][0] * di4.x);
            pk.y = f2bf(acc[nt][mt][1] * di4.y);
            pk.z = f2bf(acc[nt][mt][2] * di4.z);
            pk.w = f2bf(acc[nt][mt][3] * di4.w);
            *(ushort4*)&tT[(size_t)(b * DD + dp) * NN + node0] = pk;
        }
    }
}

// ---------------------------------------------------------------------------
// K4: agg — dist regenerated in registers; tT staged per-wave through LDS via
// global_load_lds, 2 buffers, prefetch distance 2, explicit vmcnt(8).
// No barriers in the K-loop (per-wave buffers).  Block 32n x 128d, grid 512,
// 4 waves = 4-way K-split.  Reduction buffer aliases the staging LDS.
// ---------------------------------------------------------------------------
template <bool HP>
__global__ __launch_bounds__(256, 2)
void agg_mfma(const float* __restrict__ inst, const unsigned short* __restrict__ tT,
              const float* __restrict__ dinv, const float* __restrict__ bg_l,
              const float* __restrict__ psumP, const float* __restrict__ psqP,
              const float* __restrict__ ga, const float* __restrict__ gw,
              const float* __restrict__ gb,
              float* __restrict__ h, float* __restrict__ psum, float* __restrict__ psq)
{
    __shared__ float cs[NN * 2];          // 16 KB coords
    __shared__ char  Bbuf[4][2][8192];    // 64 KB staging; aliased as red[] below
    f32x4 (*red)[16][64] = (f32x4 (*)[16][64])Bbuf;   // red[4][16][64] = 64 KB

    const int b    = blockIdx.x & 7;
    const int n0   = (blockIdx.x >> 3) * 32;
    const int tid  = threadIdx.x;
    const int w    = tid >> 6;
    const int lane = tid & 63;
    const int lq   = lane >> 4;
    const int ll   = lane & 15;

    const float* instb = inst + b * NN * 2;
    for (int i = tid; i < (NN * 2) / 4; i += 256)
        ((float4*)cs)[i] = ((const float4*)instb)[i];
    __syncthreads();

    // n-coords for this lane's 2 dist-frag rows
    float nx[2], ny[2];
    #pragma unroll
    for (int nt = 0; nt < 2; ++nt) {
        int n = n0 + nt * 16 + ll;
        nx[nt] = cs[n * 2 + 0];
        ny[nt] = cs[n * 2 + 1];
    }

    // per-lane global base for tT frags: + (dt*16+ll)*NN per dt, + kc*32 per chunk
    const unsigned short* tTb = tT + (size_t)b * DD * NN + w * 512 + lq * 8;

    f32x4 acc[2][8];   // [nt][dt]
    #pragma unroll
    for (int i = 0; i < 2; ++i)
        #pragma unroll
        for (int j = 0; j < 8; ++j) acc[i][j] = (f32x4)0.0f;

    const int mwbase = w * 512;

#define GLLB(kc_, bufp_) { \
        const int mo_ = (kc_) * 32; \
        _Pragma("unroll") \
        for (int dt_ = 0; dt_ < 8; ++dt_) \
            GLL16(tTb + (size_t)(dt_ * 16 + ll) * NN + mo_, (bufp_) + dt_ * 1024); \
    }

#define CHUNK_BODY(kc_, PREFETCH_) { \
        __builtin_amdgcn_sched_barrier(0); \
        char* bufp = &Bbuf[w][(kc_) & 1][0]; \
        bf16x8 fb[8]; \
        _Pragma("unroll") \
        for (int dt_ = 0; dt_ < 8; ++dt_) \
            fb[dt_] = *(const bf16x8*)(bufp + dt_ * 1024 + lane * 16); \
        const int mb = mwbase + (kc_) * 32; \
        const float* cp = &cs[(mb + lq * 8) * 2]; \
        float4 c01 = *(const float4*)(cp + 0); \
        float4 c23 = *(const float4*)(cp + 4); \
        float4 c45 = *(const float4*)(cp + 8); \
        float4 c67 = *(const float4*)(cp + 12); \
        __builtin_amdgcn_s_waitcnt(WAIT_LGKM0); \
        __builtin_amdgcn_sched_barrier(0); \
        if (PREFETCH_) GLLB((kc_) + 2, bufp) \
        float mxx[8] = { c01.x, c01.z, c23.x, c23.z, c45.x, c45.z, c67.x, c67.z }; \
        float myy[8] = { c01.y, c01.w, c23.y, c23.w, c45.y, c45.w, c67.y, c67.w }; \
        const bool diagchunk = (mb == n0); \
        bf16x8 bfr[2]; \
        _Pragma("unroll") \
        for (int nt_ = 0; nt_ < 2; ++nt_) { \
            float dist[8]; \
            _Pragma("unroll") \
            for (int j_ = 0; j_ < 8; ++j_) { \
                float dx = nx[nt_] - mxx[j_]; \
                float dy = ny[nt_] - myy[j_]; \
                dist[j_] = FSQRT(dx * dx + dy * dy); \
            } \
            if (diagchunk) { \
                const int nloc = nt_ * 16 + ll; \
                const int base = lq * 8; \
                _Pragma("unroll") \
                for (int j_ = 0; j_ < 8; ++j_) \
                    if (base + j_ == nloc) dist[j_] = 1.0f; \
            } \
            union { bf16x8 v; __hip_bfloat162 h2[4]; } u; \
            _Pragma("unroll") \
            for (int p_ = 0; p_ < 4; ++p_) \
                u.h2[p_] = __float22bfloat162_rn(make_float2(dist[2 * p_], dist[2 * p_ + 1])); \
            bfr[nt_] = u.v; \
        } \
        _Pragma("unroll") \
        for (int dt_ = 0; dt_ < 8; ++dt_) \
            _Pragma("unroll") \
            for (int nt_ = 0; nt_ < 2; ++nt_) \
                acc[nt_][dt_] = __builtin_amdgcn_mfma_f32_16x16x32_bf16( \
                    fb[dt_], bfr[nt_], acc[nt_][dt_], 0, 0, 0); \
    }

    // prologue: chunks 0,1 in flight (16 outstanding GLLs)
    GLLB(0, (&Bbuf[w][0][0]))
    GLLB(1, (&Bbuf[w][1][0]))

    #pragma unroll
    for (int kc = 0; kc < 15; ++kc) {
        __builtin_amdgcn_s_waitcnt(WAIT_VM8);   // chunk kc landed; kc+1 in flight
        CHUNK_BODY(kc, (kc < 14))
    }
    __builtin_amdgcn_s_waitcnt(WAIT_VM0);       // final chunk landed
    CHUNK_BODY(15, false)

#undef GLLB
#undef CHUNK_BODY

    // ---- cross-wave reduction (single round; red aliases Bbuf) + epilogue
    __syncthreads();
    #pragma unroll
    for (int nt = 0; nt < 2; ++nt)
        #pragma unroll
        for (int dt = 0; dt < 8; ++dt)
            red[w][nt * 8 + dt][lane] = acc[nt][dt];
    __syncthreads();

    #pragma unroll
    for (int i = 0; i < 4; ++i) {
        const int f  = w * 4 + i;
        const int nt = f >> 3;
        const int dt = f & 7;
        f32x4 v = red[0][f][lane];
        v += red[1][f][lane];
        v += red[2][f][lane];
        v += red[3][f][lane];

        const int n  = n0 + nt * 16 + ll;
        const int d0 = dt * 16 + lq * 4;
        const float di = dinv[b * NN + n];
        float4 bg4 = *(const float4*)&bg_l[d0];
        float sres[4] = {1.f, 1.f, 1.f, 1.f}, cres[4] = {0.f, 0.f, 0.f, 0.f};
        if (HP) {
            float4 ps4 = *(const float4*)&psumP[b * DD + d0];
            float4 pq4 = *(const float4*)&psqP[b * DD + d0];
            float4 ga4 = *(const float4*)&ga[d0];
            float4 gw4 = *(const float4*)&gw[d0];
            float4 gb4 = *(const float4*)&gb[d0];
            stats_sc(ps4.x, pq4.x, ga4.x, gw4.x, gb4.x, sres[0], cres[0]);
            stats_sc(ps4.y, pq4.y, ga4.y, gw4.y, gb4.y, sres[1], cres[1]);
            stats_sc(ps4.z, pq4.z, ga4.z, gw4.z, gb4.z, sres[2], cres[2]);
            stats_sc(ps4.w, pq4.w, ga4.w, gw4.w, gb4.w, sres[3], cres[3]);
        }
        size_t idx = ((size_t)b * NN + n) * DD + d0;
        float4 hv = *(const float4*)&h[idx];
        float outv[4];
        #pragma unroll
        for (int r = 0; r < 4; ++r) {
            float pre = di * v[r] + (&bg4.x)[r];
            outv[r] = fast_tanh(pre) + fmaf(sres[r], (&hv.x)[r], cres[r]);
        }
        float4 ov = { outv[0], outv[1], outv[2], outv[3] };
        *(float4*)&h[idx] = ov;

        // stats: per-d sums over the 16 n's (ll dimension)
        float hs[4], hq[4];
        #pragma unroll
        for (int r = 0; r < 4; ++r) { hs[r] = outv[r]; hq[r] = outv[r] * outv[r]; }
        #pragma unroll
        for (int off = 1; off < 16; off <<= 1) {
            #pragma unroll
            for (int r = 0; r < 4; ++r) {
                hs[r] += __shfl_xor(hs[r], off);
                hq[r] += __shfl_xor(hq[r], off);
            }
        }
        if (ll == 0) {
            #pragma unroll
            for (int r = 0; r < 4; ++r) {
                atomicAdd(&psum[b * DD + d0 + r], hs[r]);
                atomicAdd(&psq[b * DD + d0 + r], hq[r]);
            }
        }
    }
}

// ---------------------------------------------------------------------------
// K5: final apply with in-thread stats from layer-2 buffers
// ---------------------------------------------------------------------------
__global__ __launch_bounds__(256)
void apply_kernel(const float* __restrict__ h,
                  const float* __restrict__ psum2, const float* __restrict__ psq2,
                  const float* __restrict__ ga, const float* __restrict__ gw,
                  const float* __restrict__ gb, float* __restrict__ dst)
{
    const int i4 = blockIdx.x * 256 + threadIdx.x;    // < B*N*D/4
    const int dg = (i4 & 31) * 4;
    const int b  = i4 >> 16;                          // N*D/4 = 65536
    float4 hv = ((const float4*)h)[i4];
    float o[4];
    #pragma unroll
    for (int j = 0; j < 4; ++j) {
        const int d = dg + j;
        float s, c;
        stats_sc(psum2[b * DD + d], psq2[b * DD + d], ga[d], gw[d], gb[d], s, c);
        o[j] = fmaf(s, (&hv.x)[j], c);
    }
    float4 ov = { o[0], o[1], o[2], o[3] };
    ((float4*)dst)[i4] = ov;
}

// ---------------------------------------------------------------------------
extern "C" void kernel_launch(void* const* d_in, const int* in_sizes, int n_in,
                              void* d_out, int out_size, void* d_ws, size_t ws_size,
                              hipStream_t stream)
{
    const float* inst = (const float*)d_in[0];
    const float* Wn   = (const float*)d_in[1];
    const float* bn   = (const float*)d_in[2];
    const float* Wg   = (const float*)d_in[3];
    const float* bg   = (const float*)d_in[4];
    const float* gw   = (const float*)d_in[5];
    const float* gb   = (const float*)d_in[6];
    const float* ga   = (const float*)d_in[7];
    float* out = (float*)d_out;

    float* ws   = (float*)d_ws;
    float* dinv = ws;                                   // B*N
    float* h    = dinv + BB * NN;                       // B*N*D
    float* psum = h + (size_t)BB * NN * DD;             // LL*B*D
    float* psq  = psum + LL * BB * DD;                  // LL*B*D
    unsigned short* wgf = (unsigned short*)(psq + LL * BB * DD);  // LL*D*D bf16
    unsigned short* tT  = wgf + LL * DD * DD;                     // B*D*N bf16 (8MB)

    prep_wg<<<(LL * DD * DD) / 256, 256, 0, stream>>>(Wg, wgf);
    deg_kernel<<<BB * 64, 256, 0, stream>>>(inst, dinv);
    proj_kernel<<<(BB * NN * DD) / 256, 256, 0, stream>>>(inst, Wn, bn, h, psum, psq);

    for (int l = 0; l < LL; ++l) {
        const unsigned short* wgl = wgf + (size_t)l * DD * DD;
        const float* psP = psum + (size_t)(l - 1) * BB * DD;
        const float* pqP = psq  + (size_t)(l - 1) * BB * DD;
        float* psL = psum + (size_t)l * BB * DD;
        float* pqL = psq  + (size_t)l * BB * DD;
        if (l == 0) {
            lin_mfma<false><<<(BB * NN) / 32, 256, 0, stream>>>(
                h, wgl, dinv, nullptr, nullptr, ga, gw, gb, tT);
            agg_mfma<false><<<(NN / 32) * BB, 256, 0, stream>>>(
                inst, tT, dinv, bg + l * DD, nullptr, nullptr, ga, gw, gb, h, psL, pqL);
        } else {
            lin_mfma<true><<<(BB * NN) / 32, 256, 0, stream>>>(
                h, wgl, dinv, psP, pqP, ga, gw, gb, tT);
            agg_mfma<true><<<(NN / 32) * BB, 256, 0, stream>>>(
                inst, tT, dinv, bg + l * DD, psP, pqP, ga, gw, gb, h, psL, pqL);
        }
    }
    apply_kernel<<<(BB * NN * DD / 4) / 256, 256, 0, stream>>>(
        h, psum + 2 * BB * DD, psq + 2 * BB * DD, ga, gw, gb, out);
}